// Round 1
// baseline (6833.089 us; speedup 1.0000x reference)
//
#include <hip/hip_runtime.h>
#include <hip/hip_bf16.h>

// GNN: 3x GCNConv (25->64->64->32) + global mean pool (256 graphs) + MLP head.
// Round 0: correctness-first. Aggregation via edge-parallel f32 atomics.

#define IN_DIM 25
#define HID 64
#define OUT3 32
#define NGRAPH 32   // head hidden

// ---------------- degree ----------------
__global__ void deg_kernel(const int* __restrict__ dst, float* __restrict__ deg, int nE) {
    int e = blockIdx.x * 256 + threadIdx.x;
    if (e < nE) atomicAdd(&deg[dst[e]], 1.0f);
}

__global__ void dinv_kernel(float* __restrict__ deg, int n) {
    int i = blockIdx.x * 256 + threadIdx.x;
    if (i < n) {
        float d = deg[i] + 1.0f;          // + self loop; always >= 1
        deg[i] = 1.0f / sqrtf(d);
    }
}

// ---------------- dense layer: out = act(in) @ W ----------------
// act(in) = PREACT ? relu(in + bias_prev) : in
template<int INF, int OUTF, bool PREACT>
__global__ __launch_bounds__(256) void gemm_kernel(
        const float* __restrict__ in, const float* __restrict__ W,
        const float* __restrict__ bias_prev, float* __restrict__ out, int n) {
    constexpr int NPB = 256 / OUTF;     // nodes per block
    __shared__ float sW[INF][OUTF];
    __shared__ float sIn[NPB][INF];
    for (int i = threadIdx.x; i < INF * OUTF; i += 256)
        sW[i / OUTF][i % OUTF] = W[i];
    int node0 = blockIdx.x * NPB;
    for (int i = threadIdx.x; i < NPB * INF; i += 256) {
        int ln = i / INF, k = i % INF;
        int node = node0 + ln;
        float v = 0.f;
        if (node < n) {
            v = in[node * INF + k];
            if (PREACT) v = fmaxf(v + bias_prev[k], 0.f);
        }
        sIn[ln][k] = v;
    }
    __syncthreads();
    int ln = threadIdx.x / OUTF;
    int of = threadIdx.x % OUTF;
    int node = node0 + ln;
    if (node < n) {
        float acc = 0.f;
#pragma unroll
        for (int k = 0; k < INF; ++k) acc += sIn[ln][k] * sW[k][of];
        out[node * OUTF + of] = acc;
    }
}

// ---------------- self-loop init: agg[i] = h[i] * dinv_i^2 ----------------
template<int F>
__global__ void selfinit_kernel(const float* __restrict__ h, const float* __restrict__ dinv,
                                float* __restrict__ agg, int n) {
    int i = blockIdx.x * 256 + threadIdx.x;
    if (i < n * F) {
        int node = i / F;
        float dv = dinv[node];
        agg[i] = h[i] * dv * dv;
    }
}

// ---------------- edge scatter: agg[dst] += h[src] * dinv[src]*dinv[dst] ----------------
// F/4 threads per edge, each handles a float4 slice.
template<int F>
__global__ __launch_bounds__(256) void scatter_kernel(
        const float* __restrict__ h, const float* __restrict__ dinv,
        const int* __restrict__ src, const int* __restrict__ dst,
        float* __restrict__ agg, int nE) {
    constexpr int TPE = F / 4;
    int gid = blockIdx.x * 256 + threadIdx.x;
    int e  = gid / TPE;
    int f4 = (gid % TPE) * 4;
    if (e >= nE) return;
    int s = src[e], d = dst[e];
    float norm = dinv[s] * dinv[d];
    const float4 v = *(const float4*)&h[s * F + f4];
    float* ap = &agg[d * F + f4];
    atomicAdd(ap + 0, v.x * norm);
    atomicAdd(ap + 1, v.y * norm);
    atomicAdd(ap + 2, v.z * norm);
    atomicAdd(ap + 3, v.w * norm);
}

// ---------------- mean pool: block per graph (batch is sorted) ----------------
__global__ __launch_bounds__(256) void pool_kernel(
        const float* __restrict__ agg3, const float* __restrict__ b3,
        const int* __restrict__ batch, int n, float* __restrict__ pool) {
    int g = blockIdx.x;
    // lower_bound(batch, g)
    int lo = 0, hi = n;
    while (lo < hi) { int m = (lo + hi) >> 1; if (batch[m] < g) lo = m + 1; else hi = m; }
    int s = lo;
    hi = n;
    while (lo < hi) { int m = (lo + hi) >> 1; if (batch[m] < g + 1) lo = m + 1; else hi = m; }
    int e = lo;
    constexpr int F = OUT3;
    int ln = threadIdx.x / F;   // 0..7
    int f  = threadIdx.x % F;
    float acc = 0.f;
    for (int i = s + ln; i < e; i += 8)
        acc += fmaxf(agg3[i * F + f] + b3[f], 0.f);
    __shared__ float red[8][F];
    red[ln][f] = acc;
    __syncthreads();
    if (ln == 0) {
        float t = 0.f;
#pragma unroll
        for (int j = 0; j < 8; ++j) t += red[j][f];
        float cnt = (float)((e - s) > 0 ? (e - s) : 1);
        pool[g * F + f] = t / cnt;
    }
}

// ---------------- head: y = relu(pool @ Wh1 + bh1) @ Wh2 + bh2 ----------------
__global__ __launch_bounds__(256) void head_kernel(
        const float* __restrict__ pool, const float* __restrict__ Wh1,
        const float* __restrict__ bh1, const float* __restrict__ Wh2,
        const float* __restrict__ bh2, float* __restrict__ out) {
    __shared__ float sW1[32 * 32];
    __shared__ float sb1[32];
    __shared__ float sW2[32];
    int t = threadIdx.x;
    for (int i = t; i < 1024; i += 256) sW1[i] = Wh1[i];
    if (t < 32) { sb1[t] = bh1[t]; sW2[t] = Wh2[t]; }
    __syncthreads();
    int g = t;   // 256 graphs, 256 threads
    float y = bh2[0];
    const float* p = &pool[g * 32];
#pragma unroll 4
    for (int j = 0; j < 32; ++j) {
        float a = sb1[j];
#pragma unroll
        for (int k = 0; k < 32; ++k) a += p[k] * sW1[k * 32 + j];
        y += fmaxf(a, 0.f) * sW2[j];
    }
    out[g] = y;
}

extern "C" void kernel_launch(void* const* d_in, const int* in_sizes, int n_in,
                              void* d_out, int out_size, void* d_ws, size_t ws_size,
                              hipStream_t stream) {
    const float* x    = (const float*)d_in[0];
    const int*   ei   = (const int*)  d_in[1];
    const int*   batch= (const int*)  d_in[2];
    const float* W1   = (const float*)d_in[3];
    const float* b1   = (const float*)d_in[4];
    const float* W2   = (const float*)d_in[5];
    const float* b2   = (const float*)d_in[6];
    const float* W3   = (const float*)d_in[7];
    const float* b3   = (const float*)d_in[8];
    const float* Wh1  = (const float*)d_in[9];
    const float* bh1  = (const float*)d_in[10];
    const float* Wh2  = (const float*)d_in[11];
    const float* bh2  = (const float*)d_in[12];
    float* out = (float*)d_out;

    const int N = in_sizes[0] / IN_DIM;
    const int E = in_sizes[1] / 2;
    const int* src = ei;
    const int* dst = ei + E;

    float* ws   = (float*)d_ws;
    float* dinv = ws;              // N
    float* h    = dinv + N;        // N*64
    float* agg  = h + (size_t)N * HID;   // N*64
    float* pool = agg + (size_t)N * HID; // 256*32

    // degrees -> dinv
    hipMemsetAsync(dinv, 0, (size_t)N * sizeof(float), stream);
    deg_kernel<<<(E + 255) / 256, 256, 0, stream>>>(dst, dinv, E);
    dinv_kernel<<<(N + 255) / 256, 256, 0, stream>>>(dinv, N);

    // ---- layer 1: x(N,25) @ W1 -> h(N,64); aggregate -> agg ----
    gemm_kernel<IN_DIM, HID, false><<<(N + 3) / 4, 256, 0, stream>>>(x, W1, nullptr, h, N);
    selfinit_kernel<HID><<<((size_t)N * HID + 255) / 256, 256, 0, stream>>>(h, dinv, agg, N);
    scatter_kernel<HID><<<((size_t)E * (HID/4) + 255) / 256, 256, 0, stream>>>(h, dinv, src, dst, agg, E);

    // ---- layer 2: relu(agg+b1) @ W2 -> h; aggregate -> agg ----
    gemm_kernel<HID, HID, true><<<(N + 3) / 4, 256, 0, stream>>>(agg, W2, b1, h, N);
    selfinit_kernel<HID><<<((size_t)N * HID + 255) / 256, 256, 0, stream>>>(h, dinv, agg, N);
    scatter_kernel<HID><<<((size_t)E * (HID/4) + 255) / 256, 256, 0, stream>>>(h, dinv, src, dst, agg, E);

    // ---- layer 3: relu(agg+b2) @ W3 -> h(N,32); aggregate -> agg(N,32) ----
    gemm_kernel<HID, OUT3, true><<<(N + 7) / 8, 256, 0, stream>>>(agg, W3, b2, h, N);
    selfinit_kernel<OUT3><<<((size_t)N * OUT3 + 255) / 256, 256, 0, stream>>>(h, dinv, agg, N);
    scatter_kernel<OUT3><<<((size_t)E * (OUT3/4) + 255) / 256, 256, 0, stream>>>(h, dinv, src, dst, agg, E);

    // ---- pool + head ----
    pool_kernel<<<256, 256, 0, stream>>>(agg, b3, batch, N, pool);
    head_kernel<<<1, 256, 0, stream>>>(pool, Wh1, bh1, Wh2, bh2, out);
}

// Round 2
// 962.377 us; speedup vs baseline: 7.1002x; 7.1002x over previous
//
#include <hip/hip_runtime.h>
#include <hip/hip_bf16.h>

// GNN: 3x GCNConv (25->64->64->32) + global mean pool (256 graphs) + MLP head.
// Round 1: CSR-by-dst gather aggregation (built once per launch) instead of
// atomic scatter. Scatter was 94% of runtime at 1.3% VALUBusy with 128x HBM
// write amplification (WRITE_SIZE 3.2GB for a 25.6MB output).

#define IN_DIM 25
#define HID 64
#define OUT3 32

// ---------------- CSR build ----------------
__global__ void hist_kernel(const int* __restrict__ dst, int* __restrict__ cnt, int nE) {
    int e = blockIdx.x * 256 + threadIdx.x;
    if (e < nE) atomicAdd(&cnt[dst[e]], 1);
}

__global__ void dinv_kernel(const int* __restrict__ cnt, float* __restrict__ dinv, int n) {
    int i = blockIdx.x * 256 + threadIdx.x;
    if (i < n) dinv[i] = rsqrtf((float)cnt[i] + 1.0f);   // + self loop
}

// hierarchical exclusive scan over cnt[0..n) -> row_ptr, chunk = 2048
__global__ __launch_bounds__(256) void scan_reduce(const int* __restrict__ cnt,
                                                   int* __restrict__ bsums, int n) {
    __shared__ int sdata[256];
    int base = blockIdx.x * 2048 + threadIdx.x * 8;
    int s = 0;
#pragma unroll
    for (int j = 0; j < 8; ++j) { int i = base + j; if (i < n) s += cnt[i]; }
    sdata[threadIdx.x] = s;
    __syncthreads();
    for (int off = 128; off > 0; off >>= 1) {
        if (threadIdx.x < off) sdata[threadIdx.x] += sdata[threadIdx.x + off];
        __syncthreads();
    }
    if (threadIdx.x == 0) bsums[blockIdx.x] = sdata[0];
}

__global__ void scan_sums(int* __restrict__ bsums, int nb) {
    if (threadIdx.x == 0 && blockIdx.x == 0) {
        int acc = 0;
        for (int i = 0; i < nb; ++i) { int v = bsums[i]; bsums[i] = acc; acc += v; }
        bsums[nb] = acc;   // total
    }
}

__global__ __launch_bounds__(256) void scan_write(const int* __restrict__ cnt,
                                                  const int* __restrict__ bsums,
                                                  int* __restrict__ row_ptr, int n, int nb) {
    __shared__ int sdata[256];
    int t = threadIdx.x;
    int base = blockIdx.x * 2048 + t * 8;
    int loc[8];
    int s = 0;
#pragma unroll
    for (int j = 0; j < 8; ++j) {
        int i = base + j;
        int v = (i < n) ? cnt[i] : 0;
        loc[j] = s; s += v;
    }
    sdata[t] = s;
    __syncthreads();
    // inclusive Hillis-Steele scan across threads
    for (int off = 1; off < 256; off <<= 1) {
        int mine = sdata[t];
        int add  = (t >= off) ? sdata[t - off] : 0;
        __syncthreads();
        sdata[t] = mine + add;
        __syncthreads();
    }
    int excl = sdata[t] - s + bsums[blockIdx.x];
#pragma unroll
    for (int j = 0; j < 8; ++j) {
        int i = base + j;
        if (i < n) row_ptr[i] = excl + loc[j];
    }
    if (blockIdx.x == 0 && t == 0) row_ptr[n] = bsums[nb];
}

__global__ __launch_bounds__(256) void place_kernel(
        const int* __restrict__ src, const int* __restrict__ dst,
        const float* __restrict__ dinv, const int* __restrict__ row_ptr,
        int* __restrict__ fill, int* __restrict__ col, float* __restrict__ w, int nE) {
    int e = blockIdx.x * 256 + threadIdx.x;
    if (e >= nE) return;
    int s = src[e], d = dst[e];
    int pos = row_ptr[d] + atomicAdd(&fill[d], 1);
    col[pos] = s;
    w[pos] = dinv[s] * dinv[d];
}

// ---------------- dense layer: out = act(in) @ W ----------------
template<int INF, int OUTF, bool PREACT>
__global__ __launch_bounds__(256) void gemm_kernel(
        const float* __restrict__ in, const float* __restrict__ W,
        const float* __restrict__ bias_prev, float* __restrict__ out, int n) {
    constexpr int NPB = 256 / OUTF;
    __shared__ float sW[INF][OUTF];
    __shared__ float sIn[NPB][INF];
    for (int i = threadIdx.x; i < INF * OUTF; i += 256)
        sW[i / OUTF][i % OUTF] = W[i];
    int node0 = blockIdx.x * NPB;
    for (int i = threadIdx.x; i < NPB * INF; i += 256) {
        int ln = i / INF, k = i % INF;
        int node = node0 + ln;
        float v = 0.f;
        if (node < n) {
            v = in[node * INF + k];
            if (PREACT) v = fmaxf(v + bias_prev[k], 0.f);
        }
        sIn[ln][k] = v;
    }
    __syncthreads();
    int ln = threadIdx.x / OUTF;
    int of = threadIdx.x % OUTF;
    int node = node0 + ln;
    if (node < n) {
        float acc = 0.f;
#pragma unroll
        for (int k = 0; k < INF; ++k) acc += sIn[ln][k] * sW[k][of];
        out[node * OUTF + of] = acc;
    }
}

// ---------------- CSR gather aggregation ----------------
// One wave per (64/F) nodes; lane -> (sub-node, feature). Sequential writes.
template<int F>
__global__ __launch_bounds__(256) void gather_kernel(
        const float* __restrict__ h, const float* __restrict__ dinv,
        const int* __restrict__ row_ptr, const int* __restrict__ col,
        const float* __restrict__ w, float* __restrict__ agg, int n) {
    constexpr int NPW = 64 / F;
    int wid  = (blockIdx.x * 256 + threadIdx.x) >> 6;
    int lane = threadIdx.x & 63;
    int sub  = lane / F;
    int f    = lane % F;
    int node = wid * NPW + sub;
    if (node >= n) return;
    float dv = dinv[node];
    float acc = h[(size_t)node * F + f] * dv * dv;   // self loop
    int e = row_ptr[node], end = row_ptr[node + 1];
    for (; e + 4 <= end; e += 4) {
        int   s0 = col[e], s1 = col[e+1], s2 = col[e+2], s3 = col[e+3];
        float w0 = w[e],   w1 = w[e+1],   w2 = w[e+2],   w3 = w[e+3];
        float v0 = h[(size_t)s0 * F + f];
        float v1 = h[(size_t)s1 * F + f];
        float v2 = h[(size_t)s2 * F + f];
        float v3 = h[(size_t)s3 * F + f];
        acc += v0 * w0 + v1 * w1 + v2 * w2 + v3 * w3;
    }
    for (; e < end; ++e) acc += h[(size_t)col[e] * F + f] * w[e];
    agg[(size_t)node * F + f] = acc;
}

// ---------------- mean pool: block per graph (batch is sorted) ----------------
__global__ __launch_bounds__(256) void pool_kernel(
        const float* __restrict__ agg3, const float* __restrict__ b3,
        const int* __restrict__ batch, int n, float* __restrict__ pool) {
    int g = blockIdx.x;
    int lo = 0, hi = n;
    while (lo < hi) { int m = (lo + hi) >> 1; if (batch[m] < g) lo = m + 1; else hi = m; }
    int s = lo;
    hi = n;
    while (lo < hi) { int m = (lo + hi) >> 1; if (batch[m] < g + 1) lo = m + 1; else hi = m; }
    int e = lo;
    constexpr int F = OUT3;
    int ln = threadIdx.x / F;
    int f  = threadIdx.x % F;
    float acc = 0.f;
    for (int i = s + ln; i < e; i += 8)
        acc += fmaxf(agg3[i * F + f] + b3[f], 0.f);
    __shared__ float red[8][F];
    red[ln][f] = acc;
    __syncthreads();
    if (ln == 0) {
        float t = 0.f;
#pragma unroll
        for (int j = 0; j < 8; ++j) t += red[j][f];
        float cnt = (float)((e - s) > 0 ? (e - s) : 1);
        pool[g * F + f] = t / cnt;
    }
}

// ---------------- head ----------------
__global__ __launch_bounds__(256) void head_kernel(
        const float* __restrict__ pool, const float* __restrict__ Wh1,
        const float* __restrict__ bh1, const float* __restrict__ Wh2,
        const float* __restrict__ bh2, float* __restrict__ out) {
    __shared__ float sW1[32 * 32];
    __shared__ float sb1[32];
    __shared__ float sW2[32];
    int t = threadIdx.x;
    for (int i = t; i < 1024; i += 256) sW1[i] = Wh1[i];
    if (t < 32) { sb1[t] = bh1[t]; sW2[t] = Wh2[t]; }
    __syncthreads();
    int g = t;
    float y = bh2[0];
    const float* p = &pool[g * 32];
#pragma unroll 4
    for (int j = 0; j < 32; ++j) {
        float a = sb1[j];
#pragma unroll
        for (int k = 0; k < 32; ++k) a += p[k] * sW1[k * 32 + j];
        y += fmaxf(a, 0.f) * sW2[j];
    }
    out[g] = y;
}

extern "C" void kernel_launch(void* const* d_in, const int* in_sizes, int n_in,
                              void* d_out, int out_size, void* d_ws, size_t ws_size,
                              hipStream_t stream) {
    const float* x    = (const float*)d_in[0];
    const int*   ei   = (const int*)  d_in[1];
    const int*   batch= (const int*)  d_in[2];
    const float* W1   = (const float*)d_in[3];
    const float* b1   = (const float*)d_in[4];
    const float* W2   = (const float*)d_in[5];
    const float* b2   = (const float*)d_in[6];
    const float* W3   = (const float*)d_in[7];
    const float* b3   = (const float*)d_in[8];
    const float* Wh1  = (const float*)d_in[9];
    const float* bh1  = (const float*)d_in[10];
    const float* Wh2  = (const float*)d_in[11];
    const float* bh2  = (const float*)d_in[12];
    float* out = (float*)d_out;

    const int N = in_sizes[0] / IN_DIM;
    const int E = in_sizes[1] / 2;
    const int* src = ei;
    const int* dst = ei + E;
    const int NB_SCAN = (N + 2047) / 2048;

    // workspace layout (all 4-byte elements)
    char* base = (char*)d_ws;
    int*   row_ptr = (int*)base;                    base += (size_t)(N + 1) * 4;
    int*   fill    = (int*)base;                    base += (size_t)N * 4;
    int*   bsums   = (int*)base;                    base += (size_t)(NB_SCAN + 8) * 4;
    int*   col     = (int*)base;                    base += (size_t)E * 4;
    float* w       = (float*)base;                  base += (size_t)E * 4;
    float* dinv    = (float*)base;                  base += (size_t)N * 4;
    float* h       = (float*)base;                  base += (size_t)N * HID * 4;
    float* agg     = (float*)base;                  base += (size_t)N * HID * 4;
    float* pool    = (float*)base;

    // ---- CSR build ----
    hipMemsetAsync(fill, 0, (size_t)N * sizeof(int), stream);
    hist_kernel<<<(E + 255) / 256, 256, 0, stream>>>(dst, fill, E);
    dinv_kernel<<<(N + 255) / 256, 256, 0, stream>>>(fill, dinv, N);
    scan_reduce<<<NB_SCAN, 256, 0, stream>>>(fill, bsums, N);
    scan_sums<<<1, 64, 0, stream>>>(bsums, NB_SCAN);
    scan_write<<<NB_SCAN, 256, 0, stream>>>(fill, bsums, row_ptr, N, NB_SCAN);
    hipMemsetAsync(fill, 0, (size_t)N * sizeof(int), stream);
    place_kernel<<<(E + 255) / 256, 256, 0, stream>>>(src, dst, dinv, row_ptr, fill, col, w, E);

    // ---- layer 1: x(N,25) @ W1 -> h(N,64); gather -> agg ----
    gemm_kernel<IN_DIM, HID, false><<<(N + 3) / 4, 256, 0, stream>>>(x, W1, nullptr, h, N);
    gather_kernel<HID><<<(N + 3) / 4, 256, 0, stream>>>(h, dinv, row_ptr, col, w, agg, N);

    // ---- layer 2 ----
    gemm_kernel<HID, HID, true><<<(N + 3) / 4, 256, 0, stream>>>(agg, W2, b1, h, N);
    gather_kernel<HID><<<(N + 3) / 4, 256, 0, stream>>>(h, dinv, row_ptr, col, w, agg, N);

    // ---- layer 3 (32-wide) ----
    gemm_kernel<HID, OUT3, true><<<(N + 7) / 8, 256, 0, stream>>>(agg, W3, b2, h, N);
    gather_kernel<OUT3><<<(N + 7) / 8, 256, 0, stream>>>(h, dinv, row_ptr, col, w, agg, N);

    // ---- pool + head ----
    pool_kernel<<<256, 256, 0, stream>>>(agg, b3, batch, N, pool);
    head_kernel<<<1, 256, 0, stream>>>(pool, Wh1, bh1, Wh2, bh2, out);
}

// Round 3
// 863.781 us; speedup vs baseline: 7.9107x; 1.1141x over previous
//
#include <hip/hip_runtime.h>
#include <hip/hip_bf16.h>

// GNN: 3x GCNConv (25->64->64->32) + global mean pool (256 graphs) + MLP head.
// Round 2: (a) CSR edge payload packed to one float2 (col,w) -> single 8B
// random store in place_kernel (was 2x 4B stores to separate arrays = 11x
// HBM write amplification); (b) register-tiled GEMM with ds_read_b128
// (was 2 scalar LDS reads per FMA); (c) relu+bias fused into gather epilogue.

#define IN_DIM 25
#define HID 64
#define OUT3 32

// ---------------- CSR build ----------------
__global__ void hist_kernel(const int* __restrict__ dst, int* __restrict__ cnt, int nE) {
    int e = blockIdx.x * 256 + threadIdx.x;
    if (e < nE) atomicAdd(&cnt[dst[e]], 1);
}

__global__ void dinv_kernel(const int* __restrict__ cnt, float* __restrict__ dinv, int n) {
    int i = blockIdx.x * 256 + threadIdx.x;
    if (i < n) dinv[i] = rsqrtf((float)cnt[i] + 1.0f);   // + self loop
}

// hierarchical exclusive scan over cnt[0..n) -> row_ptr (+ mutable copy rpc)
__global__ __launch_bounds__(256) void scan_reduce(const int* __restrict__ cnt,
                                                   int* __restrict__ bsums, int n) {
    __shared__ int sdata[256];
    int base = blockIdx.x * 2048 + threadIdx.x * 8;
    int s = 0;
#pragma unroll
    for (int j = 0; j < 8; ++j) { int i = base + j; if (i < n) s += cnt[i]; }
    sdata[threadIdx.x] = s;
    __syncthreads();
    for (int off = 128; off > 0; off >>= 1) {
        if (threadIdx.x < off) sdata[threadIdx.x] += sdata[threadIdx.x + off];
        __syncthreads();
    }
    if (threadIdx.x == 0) bsums[blockIdx.x] = sdata[0];
}

__global__ void scan_sums(int* __restrict__ bsums, int nb) {
    if (threadIdx.x == 0 && blockIdx.x == 0) {
        int acc = 0;
        for (int i = 0; i < nb; ++i) { int v = bsums[i]; bsums[i] = acc; acc += v; }
        bsums[nb] = acc;   // total
    }
}

__global__ __launch_bounds__(256) void scan_write(const int* __restrict__ cnt,
                                                  const int* __restrict__ bsums,
                                                  int* __restrict__ row_ptr,
                                                  int* __restrict__ rpc, int n, int nb) {
    __shared__ int sdata[256];
    int t = threadIdx.x;
    int base = blockIdx.x * 2048 + t * 8;
    int loc[8];
    int s = 0;
#pragma unroll
    for (int j = 0; j < 8; ++j) {
        int i = base + j;
        int v = (i < n) ? cnt[i] : 0;
        loc[j] = s; s += v;
    }
    sdata[t] = s;
    __syncthreads();
    for (int off = 1; off < 256; off <<= 1) {
        int mine = sdata[t];
        int add  = (t >= off) ? sdata[t - off] : 0;
        __syncthreads();
        sdata[t] = mine + add;
        __syncthreads();
    }
    int excl = sdata[t] - s + bsums[blockIdx.x];
#pragma unroll
    for (int j = 0; j < 8; ++j) {
        int i = base + j;
        if (i < n) { row_ptr[i] = excl + loc[j]; rpc[i] = excl + loc[j]; }
    }
    if (blockIdx.x == 0 && t == 0) row_ptr[n] = bsums[nb];
}

// packed edge: .x = __int_as_float(src), .y = norm weight
__global__ __launch_bounds__(256) void place_kernel(
        const int* __restrict__ src, const int* __restrict__ dst,
        const float* __restrict__ dinv, int* __restrict__ rpc,
        float2* __restrict__ ep, int nE) {
    int e = blockIdx.x * 256 + threadIdx.x;
    if (e >= nE) return;
    int s = src[e], d = dst[e];
    int pos = atomicAdd(&rpc[d], 1);
    float2 p;
    p.x = __int_as_float(s);
    p.y = dinv[s] * dinv[d];
    ep[pos] = p;
}

// ---------------- dense layer: out = in @ W (in already activated) ----------------
// Each thread computes a float4 of outputs for one node.
template<int INF, int OUTF>
__global__ __launch_bounds__(256) void gemm_kernel(
        const float* __restrict__ in, const float* __restrict__ W,
        float* __restrict__ out, int n) {
    constexpr int TPN = OUTF / 4;        // threads per node (16 or 8)
    constexpr int NPB = 256 / TPN;       // nodes per block (16 or 32)
    constexpr int LDK = (INF + 4) & ~3;  // padded row stride (16B aligned, bank-spread)
    __shared__ float sW[INF * OUTF];
    __shared__ float sIn[NPB][LDK];
    for (int i = threadIdx.x; i < INF * OUTF; i += 256) sW[i] = W[i];
    int node0 = blockIdx.x * NPB;
    for (int i = threadIdx.x; i < NPB * INF; i += 256) {
        int ln = i / INF, k = i % INF;
        int node = node0 + ln;
        sIn[ln][k] = (node < n) ? in[(size_t)node * INF + k] : 0.f;
    }
    __syncthreads();
    int g   = threadIdx.x / TPN;          // node sub-index
    int of0 = (threadIdx.x % TPN) * 4;    // output feature base
    int node = node0 + g;
    float4 acc = make_float4(0.f, 0.f, 0.f, 0.f);
#pragma unroll
    for (int k4 = 0; k4 < INF / 4; ++k4) {
        float4 a = *(const float4*)&sIn[g][4 * k4];
#pragma unroll
        for (int j = 0; j < 4; ++j) {
            float aj = (&a.x)[j];
            const float4 wv = *(const float4*)&sW[(4 * k4 + j) * OUTF + of0];
            acc.x += aj * wv.x; acc.y += aj * wv.y;
            acc.z += aj * wv.z; acc.w += aj * wv.w;
        }
    }
#pragma unroll
    for (int k = (INF / 4) * 4; k < INF; ++k) {    // tail (INF=25)
        float aj = sIn[g][k];
        const float4 wv = *(const float4*)&sW[k * OUTF + of0];
        acc.x += aj * wv.x; acc.y += aj * wv.y;
        acc.z += aj * wv.z; acc.w += aj * wv.w;
    }
    if (node < n) *(float4*)&out[(size_t)node * OUTF + of0] = acc;
}

// ---------------- CSR gather aggregation + fused relu(acc + bias) ----------------
template<int F>
__global__ __launch_bounds__(256) void gather_kernel(
        const float* __restrict__ h, const float* __restrict__ dinv,
        const int* __restrict__ row_ptr, const float2* __restrict__ ep,
        const float* __restrict__ bias, float* __restrict__ agg, int n) {
    constexpr int NPW = 64 / F;
    int wid  = (blockIdx.x * 256 + threadIdx.x) >> 6;
    int lane = threadIdx.x & 63;
    int sub  = lane / F;
    int f    = lane % F;
    int node = wid * NPW + sub;
    if (node >= n) return;
    float dv = dinv[node];
    float acc = h[(size_t)node * F + f] * dv * dv;   // self loop
    int e = row_ptr[node], end = row_ptr[node + 1];
    for (; e + 4 <= end; e += 4) {
        float2 p0 = ep[e],   p1 = ep[e+1], p2 = ep[e+2], p3 = ep[e+3];
        int s0 = __float_as_int(p0.x), s1 = __float_as_int(p1.x);
        int s2 = __float_as_int(p2.x), s3 = __float_as_int(p3.x);
        float v0 = h[(size_t)s0 * F + f];
        float v1 = h[(size_t)s1 * F + f];
        float v2 = h[(size_t)s2 * F + f];
        float v3 = h[(size_t)s3 * F + f];
        acc += v0 * p0.y + v1 * p1.y + v2 * p2.y + v3 * p3.y;
    }
    for (; e < end; ++e) {
        float2 p = ep[e];
        acc += h[(size_t)__float_as_int(p.x) * F + f] * p.y;
    }
    agg[(size_t)node * F + f] = fmaxf(acc + bias[f], 0.f);   // fused activation
}

// ---------------- mean pool: block per graph (batch sorted; agg pre-activated) ----
__global__ __launch_bounds__(256) void pool_kernel(
        const float* __restrict__ agg3, const int* __restrict__ batch,
        int n, float* __restrict__ pool) {
    int g = blockIdx.x;
    int lo = 0, hi = n;
    while (lo < hi) { int m = (lo + hi) >> 1; if (batch[m] < g) lo = m + 1; else hi = m; }
    int s = lo;
    hi = n;
    while (lo < hi) { int m = (lo + hi) >> 1; if (batch[m] < g + 1) lo = m + 1; else hi = m; }
    int e = lo;
    constexpr int F = OUT3;
    int ln = threadIdx.x / F;
    int f  = threadIdx.x % F;
    float acc = 0.f;
    for (int i = s + ln; i < e; i += 8)
        acc += agg3[(size_t)i * F + f];
    __shared__ float red[8][F];
    red[ln][f] = acc;
    __syncthreads();
    if (ln == 0) {
        float t = 0.f;
#pragma unroll
        for (int j = 0; j < 8; ++j) t += red[j][f];
        float cnt = (float)((e - s) > 0 ? (e - s) : 1);
        pool[g * F + f] = t / cnt;
    }
}

// ---------------- head ----------------
__global__ __launch_bounds__(256) void head_kernel(
        const float* __restrict__ pool, const float* __restrict__ Wh1,
        const float* __restrict__ bh1, const float* __restrict__ Wh2,
        const float* __restrict__ bh2, float* __restrict__ out) {
    __shared__ float sW1[32 * 32];
    __shared__ float sb1[32];
    __shared__ float sW2[32];
    int t = threadIdx.x;
    for (int i = t; i < 1024; i += 256) sW1[i] = Wh1[i];
    if (t < 32) { sb1[t] = bh1[t]; sW2[t] = Wh2[t]; }
    __syncthreads();
    int g = t;
    float y = bh2[0];
    const float* p = &pool[g * 32];
#pragma unroll 4
    for (int j = 0; j < 32; ++j) {
        float a = sb1[j];
#pragma unroll
        for (int k = 0; k < 32; ++k) a += p[k] * sW1[k * 32 + j];
        y += fmaxf(a, 0.f) * sW2[j];
    }
    out[g] = y;
}

extern "C" void kernel_launch(void* const* d_in, const int* in_sizes, int n_in,
                              void* d_out, int out_size, void* d_ws, size_t ws_size,
                              hipStream_t stream) {
    const float* x    = (const float*)d_in[0];
    const int*   ei   = (const int*)  d_in[1];
    const int*   batch= (const int*)  d_in[2];
    const float* W1   = (const float*)d_in[3];
    const float* b1   = (const float*)d_in[4];
    const float* W2   = (const float*)d_in[5];
    const float* b2   = (const float*)d_in[6];
    const float* W3   = (const float*)d_in[7];
    const float* b3   = (const float*)d_in[8];
    const float* Wh1  = (const float*)d_in[9];
    const float* bh1  = (const float*)d_in[10];
    const float* Wh2  = (const float*)d_in[11];
    const float* bh2  = (const float*)d_in[12];
    float* out = (float*)d_out;

    const int N = in_sizes[0] / IN_DIM;
    const int E = in_sizes[1] / 2;
    const int* src = ei;
    const int* dst = ei + E;
    const int NB_SCAN = (N + 2047) / 2048;

    // workspace layout (float2 array first for 8B alignment)
    char* base = (char*)d_ws;
    float2* ep     = (float2*)base;                 base += (size_t)E * 8;
    int*   cnt     = (int*)base;                    base += (size_t)N * 4;
    int*   row_ptr = (int*)base;                    base += (size_t)(N + 1) * 4;
    int*   rpc     = (int*)base;                    base += (size_t)N * 4;
    int*   bsums   = (int*)base;                    base += (size_t)(NB_SCAN + 8) * 4;
    float* dinv    = (float*)base;                  base += (size_t)N * 4;
    float* h       = (float*)base;                  base += (size_t)N * HID * 4;
    float* agg     = (float*)base;                  base += (size_t)N * HID * 4;
    float* pool    = (float*)base;

    // ---- CSR build ----
    hipMemsetAsync(cnt, 0, (size_t)N * sizeof(int), stream);
    hist_kernel<<<(E + 255) / 256, 256, 0, stream>>>(dst, cnt, E);
    dinv_kernel<<<(N + 255) / 256, 256, 0, stream>>>(cnt, dinv, N);
    scan_reduce<<<NB_SCAN, 256, 0, stream>>>(cnt, bsums, N);
    scan_sums<<<1, 64, 0, stream>>>(bsums, NB_SCAN);
    scan_write<<<NB_SCAN, 256, 0, stream>>>(cnt, bsums, row_ptr, rpc, N, NB_SCAN);
    place_kernel<<<(E + 255) / 256, 256, 0, stream>>>(src, dst, dinv, rpc, ep, E);

    // ---- layer 1: x(N,25) @ W1 -> h(N,64); gather+relu(+b1) -> agg ----
    gemm_kernel<IN_DIM, HID><<<(N + 15) / 16, 256, 0, stream>>>(x, W1, h, N);
    gather_kernel<HID><<<(N + 3) / 4, 256, 0, stream>>>(h, dinv, row_ptr, ep, b1, agg, N);

    // ---- layer 2 ----
    gemm_kernel<HID, HID><<<(N + 15) / 16, 256, 0, stream>>>(agg, W2, h, N);
    gather_kernel<HID><<<(N + 3) / 4, 256, 0, stream>>>(h, dinv, row_ptr, ep, b2, agg, N);

    // ---- layer 3 (32-wide) ----
    gemm_kernel<HID, OUT3><<<(N + 31) / 32, 256, 0, stream>>>(agg, W3, h, N);
    gather_kernel<OUT3><<<(N + 7) / 8, 256, 0, stream>>>(h, dinv, row_ptr, ep, b3, agg, N);

    // ---- pool + head ----
    pool_kernel<<<256, 256, 0, stream>>>(agg, batch, N, pool);
    head_kernel<<<1, 256, 0, stream>>>(pool, Wh1, bh1, Wh2, bh2, out);
}

// Round 4
// 825.544 us; speedup vs baseline: 8.2771x; 1.0463x over previous
//
#include <hip/hip_runtime.h>
#include <hip/hip_bf16.h>

// GNN: 3x GCNConv (25->64->64->32) + global mean pool (256 graphs) + MLP head.
// Round 3: (a) layer-1 reordered as (A_hat X) W1 -- aggregation runs on the
// 32-padded input (128 B/edge) instead of 64-wide h1 (256 B/edge), halving
// gather-1 traffic; (b) place_kernel runs 8 dst-range passes (blockIdx.y) so
// random ep stores stay within a ~3.2MB window -> lines fill in L2 before
// eviction (WRITE_SIZE was 200MB for a 25.6MB payload); (c) gather unroll 8.

#define IN_DIM 25
#define HID 64
#define OUT3 32

// ---------------- CSR build ----------------
__global__ void hist_kernel(const int* __restrict__ dst, int* __restrict__ cnt, int nE) {
    int e = blockIdx.x * 256 + threadIdx.x;
    if (e < nE) atomicAdd(&cnt[dst[e]], 1);
}

__global__ void dinv_kernel(const int* __restrict__ cnt, float* __restrict__ dinv, int n) {
    int i = blockIdx.x * 256 + threadIdx.x;
    if (i < n) dinv[i] = rsqrtf((float)cnt[i] + 1.0f);   // + self loop
}

__global__ __launch_bounds__(256) void scan_reduce(const int* __restrict__ cnt,
                                                   int* __restrict__ bsums, int n) {
    __shared__ int sdata[256];
    int base = blockIdx.x * 2048 + threadIdx.x * 8;
    int s = 0;
#pragma unroll
    for (int j = 0; j < 8; ++j) { int i = base + j; if (i < n) s += cnt[i]; }
    sdata[threadIdx.x] = s;
    __syncthreads();
    for (int off = 128; off > 0; off >>= 1) {
        if (threadIdx.x < off) sdata[threadIdx.x] += sdata[threadIdx.x + off];
        __syncthreads();
    }
    if (threadIdx.x == 0) bsums[blockIdx.x] = sdata[0];
}

__global__ void scan_sums(int* __restrict__ bsums, int nb) {
    if (threadIdx.x == 0 && blockIdx.x == 0) {
        int acc = 0;
        for (int i = 0; i < nb; ++i) { int v = bsums[i]; bsums[i] = acc; acc += v; }
        bsums[nb] = acc;
    }
}

__global__ __launch_bounds__(256) void scan_write(const int* __restrict__ cnt,
                                                  const int* __restrict__ bsums,
                                                  int* __restrict__ row_ptr,
                                                  int* __restrict__ rpc, int n, int nb) {
    __shared__ int sdata[256];
    int t = threadIdx.x;
    int base = blockIdx.x * 2048 + t * 8;
    int loc[8];
    int s = 0;
#pragma unroll
    for (int j = 0; j < 8; ++j) {
        int i = base + j;
        int v = (i < n) ? cnt[i] : 0;
        loc[j] = s; s += v;
    }
    sdata[t] = s;
    __syncthreads();
    for (int off = 1; off < 256; off <<= 1) {
        int mine = sdata[t];
        int add  = (t >= off) ? sdata[t - off] : 0;
        __syncthreads();
        sdata[t] = mine + add;
        __syncthreads();
    }
    int excl = sdata[t] - s + bsums[blockIdx.x];
#pragma unroll
    for (int j = 0; j < 8; ++j) {
        int i = base + j;
        if (i < n) { row_ptr[i] = excl + loc[j]; rpc[i] = excl + loc[j]; }
    }
    if (blockIdx.x == 0 && t == 0) row_ptr[n] = bsums[nb];
}

// 8 dst-range passes via blockIdx.y: keeps the random ep writes in a small
// window so L2 lines fill before writeback.
__global__ __launch_bounds__(256) void place_kernel(
        const int* __restrict__ src, const int* __restrict__ dst,
        const float* __restrict__ dinv, int* __restrict__ rpc,
        float2* __restrict__ ep, int nE, int chunk) {
    int e = blockIdx.x * 256 + threadIdx.x;
    if (e >= nE) return;
    int d = dst[e];
    int lo = blockIdx.y * chunk;
    if (d < lo || d >= lo + chunk) return;
    int s = src[e];
    int pos = atomicAdd(&rpc[d], 1);
    float2 p;
    p.x = __int_as_float(s);
    p.y = dinv[s] * dinv[d];
    ep[pos] = p;
}

// ---------------- pad helpers ----------------
__global__ void padx_kernel(const float* __restrict__ x, float* __restrict__ xp, int n) {
    int i = blockIdx.x * 256 + threadIdx.x;
    if (i < n * 32) {
        int node = i >> 5, c = i & 31;
        xp[i] = (c < IN_DIM) ? x[(size_t)node * IN_DIM + c] : 0.f;
    }
}

__global__ void padw_kernel(const float* __restrict__ W1, float* __restrict__ W1p) {
    int i = blockIdx.x * 256 + threadIdx.x;
    if (i < 32 * HID) {
        int r = i >> 6, c = i & 63;
        W1p[i] = (r < IN_DIM) ? W1[r * HID + c] : 0.f;
    }
}

// ---------------- dense layer: out = in @ W [+ bias, relu] ----------------
template<int INF, int OUTF, bool ACT>
__global__ __launch_bounds__(256) void gemm_kernel(
        const float* __restrict__ in, const float* __restrict__ W,
        const float* __restrict__ bias, float* __restrict__ out, int n) {
    constexpr int TPN = OUTF / 4;
    constexpr int NPB = 256 / TPN;
    constexpr int LDK = INF + 4;
    __shared__ float sW[INF * OUTF];
    __shared__ float sIn[NPB][LDK];
    for (int i = threadIdx.x; i < INF * OUTF; i += 256) sW[i] = W[i];
    int node0 = blockIdx.x * NPB;
    for (int i = threadIdx.x; i < NPB * INF; i += 256) {
        int ln = i / INF, k = i % INF;
        int node = node0 + ln;
        sIn[ln][k] = (node < n) ? in[(size_t)node * INF + k] : 0.f;
    }
    __syncthreads();
    int g   = threadIdx.x / TPN;
    int of0 = (threadIdx.x % TPN) * 4;
    int node = node0 + g;
    float4 acc = make_float4(0.f, 0.f, 0.f, 0.f);
#pragma unroll
    for (int k = 0; k < INF; ++k) {
        float aj = sIn[g][k];
        const float4 wv = *(const float4*)&sW[k * OUTF + of0];
        acc.x += aj * wv.x; acc.y += aj * wv.y;
        acc.z += aj * wv.z; acc.w += aj * wv.w;
    }
    if (ACT) {
        const float4 bv = *(const float4*)&bias[of0];
        acc.x = fmaxf(acc.x + bv.x, 0.f);
        acc.y = fmaxf(acc.y + bv.y, 0.f);
        acc.z = fmaxf(acc.z + bv.z, 0.f);
        acc.w = fmaxf(acc.w + bv.w, 0.f);
    }
    if (node < n) *(float4*)&out[(size_t)node * OUTF + of0] = acc;
}

// ---------------- CSR gather aggregation [+ fused relu(acc + bias)] --------
template<int F, bool ACT>
__global__ __launch_bounds__(256) void gather_kernel(
        const float* __restrict__ h, const float* __restrict__ dinv,
        const int* __restrict__ row_ptr, const float2* __restrict__ ep,
        const float* __restrict__ bias, float* __restrict__ agg, int n) {
    constexpr int NPW = 64 / F;
    int wid  = (blockIdx.x * 256 + threadIdx.x) >> 6;
    int lane = threadIdx.x & 63;
    int sub  = lane / F;
    int f    = lane % F;
    int node = wid * NPW + sub;
    if (node >= n) return;
    float dv = dinv[node];
    float acc = h[(size_t)node * F + f] * dv * dv;   // self loop
    int e = row_ptr[node], end = row_ptr[node + 1];
    for (; e + 8 <= end; e += 8) {
        float2 p[8];
        float  v[8];
#pragma unroll
        for (int j = 0; j < 8; ++j) p[j] = ep[e + j];
#pragma unroll
        for (int j = 0; j < 8; ++j) v[j] = h[(size_t)__float_as_int(p[j].x) * F + f];
#pragma unroll
        for (int j = 0; j < 8; ++j) acc += v[j] * p[j].y;
    }
    for (; e + 2 <= end; e += 2) {
        float2 p0 = ep[e], p1 = ep[e + 1];
        float v0 = h[(size_t)__float_as_int(p0.x) * F + f];
        float v1 = h[(size_t)__float_as_int(p1.x) * F + f];
        acc += v0 * p0.y + v1 * p1.y;
    }
    if (e < end) {
        float2 p = ep[e];
        acc += h[(size_t)__float_as_int(p.x) * F + f] * p.y;
    }
    float r = ACT ? fmaxf(acc + bias[f], 0.f) : acc;
    agg[(size_t)node * F + f] = r;
}

// ---------------- mean pool: block per graph (batch sorted; input activated) ----
__global__ __launch_bounds__(256) void pool_kernel(
        const float* __restrict__ h3, const int* __restrict__ batch,
        int n, float* __restrict__ pool) {
    int g = blockIdx.x;
    int lo = 0, hi = n;
    while (lo < hi) { int m = (lo + hi) >> 1; if (batch[m] < g) lo = m + 1; else hi = m; }
    int s = lo;
    hi = n;
    while (lo < hi) { int m = (lo + hi) >> 1; if (batch[m] < g + 1) lo = m + 1; else hi = m; }
    int e = lo;
    constexpr int F = OUT3;
    int ln = threadIdx.x / F;
    int f  = threadIdx.x % F;
    float acc = 0.f;
    for (int i = s + ln; i < e; i += 8)
        acc += h3[(size_t)i * F + f];
    __shared__ float red[8][F];
    red[ln][f] = acc;
    __syncthreads();
    if (ln == 0) {
        float t = 0.f;
#pragma unroll
        for (int j = 0; j < 8; ++j) t += red[j][f];
        float cnt = (float)((e - s) > 0 ? (e - s) : 1);
        pool[g * F + f] = t / cnt;
    }
}

// ---------------- head ----------------
__global__ __launch_bounds__(256) void head_kernel(
        const float* __restrict__ pool, const float* __restrict__ Wh1,
        const float* __restrict__ bh1, const float* __restrict__ Wh2,
        const float* __restrict__ bh2, float* __restrict__ out) {
    __shared__ float sW1[32 * 32];
    __shared__ float sb1[32];
    __shared__ float sW2[32];
    int t = threadIdx.x;
    for (int i = t; i < 1024; i += 256) sW1[i] = Wh1[i];
    if (t < 32) { sb1[t] = bh1[t]; sW2[t] = Wh2[t]; }
    __syncthreads();
    int g = t;
    float y = bh2[0];
    const float* p = &pool[g * 32];
#pragma unroll 4
    for (int j = 0; j < 32; ++j) {
        float a = sb1[j];
#pragma unroll
        for (int k = 0; k < 32; ++k) a += p[k] * sW1[k * 32 + j];
        y += fmaxf(a, 0.f) * sW2[j];
    }
    out[g] = y;
}

extern "C" void kernel_launch(void* const* d_in, const int* in_sizes, int n_in,
                              void* d_out, int out_size, void* d_ws, size_t ws_size,
                              hipStream_t stream) {
    const float* x    = (const float*)d_in[0];
    const int*   ei   = (const int*)  d_in[1];
    const int*   batch= (const int*)  d_in[2];
    const float* W1   = (const float*)d_in[3];
    const float* b1   = (const float*)d_in[4];
    const float* W2   = (const float*)d_in[5];
    const float* b2   = (const float*)d_in[6];
    const float* W3   = (const float*)d_in[7];
    const float* b3   = (const float*)d_in[8];
    const float* Wh1  = (const float*)d_in[9];
    const float* bh1  = (const float*)d_in[10];
    const float* Wh2  = (const float*)d_in[11];
    const float* bh2  = (const float*)d_in[12];
    float* out = (float*)d_out;

    const int N = in_sizes[0] / IN_DIM;
    const int E = in_sizes[1] / 2;
    const int* src = ei;
    const int* dst = ei + E;
    const int NB_SCAN = (N + 2047) / 2048;

    // workspace layout
    char* base = (char*)d_ws;
    float2* ep     = (float2*)base;                 base += (size_t)E * 8;
    int*   cnt     = (int*)base;                    base += (size_t)N * 4;
    int*   row_ptr = (int*)base;                    base += (size_t)(N + 1) * 4;
    int*   rpc     = (int*)base;                    base += (size_t)N * 4;
    int*   bsums   = (int*)base;                    base += (size_t)(NB_SCAN + 8) * 4;
    float* dinv    = (float*)base;                  base += (size_t)N * 4;
    float* W1p     = (float*)base;                  base += (size_t)32 * HID * 4;
    float* bufA    = (float*)base;                  base += (size_t)N * HID * 4;  // "h"
    float* bufB    = (float*)base;                  base += (size_t)N * HID * 4;  // "agg"
    float* pool    = (float*)base;

    // ---- CSR build ----
    hipMemsetAsync(cnt, 0, (size_t)N * sizeof(int), stream);
    hist_kernel<<<(E + 255) / 256, 256, 0, stream>>>(dst, cnt, E);
    dinv_kernel<<<(N + 255) / 256, 256, 0, stream>>>(cnt, dinv, N);
    scan_reduce<<<NB_SCAN, 256, 0, stream>>>(cnt, bsums, N);
    scan_sums<<<1, 64, 0, stream>>>(bsums, NB_SCAN);
    scan_write<<<NB_SCAN, 256, 0, stream>>>(cnt, bsums, row_ptr, rpc, N, NB_SCAN);
    {
        const int chunk = (N + 7) / 8;
        dim3 grid((E + 255) / 256, 8);
        place_kernel<<<grid, 256, 0, stream>>>(src, dst, dinv, rpc, ep, E, chunk);
    }

    // ---- layer 1 (reordered): aggX = A_hat Xp ; h1 = relu(aggX @ W1p + b1) ----
    padx_kernel<<<((size_t)N * 32 + 255) / 256, 256, 0, stream>>>(x, bufB, N);   // Xp in bufB
    padw_kernel<<<(32 * HID + 255) / 256, 256, 0, stream>>>(W1, W1p);
    gather_kernel<32, false><<<(N + 7) / 8, 256, 0, stream>>>(bufB, dinv, row_ptr, ep, nullptr, bufA, N); // aggX -> bufA
    gemm_kernel<32, HID, true><<<(N + 15) / 16, 256, 0, stream>>>(bufA, W1p, b1, bufB, N);               // h1 -> bufB

    // ---- layer 2: t2 = h1 @ W2 ; h2 = relu(A_hat t2 + b2) ----
    gemm_kernel<HID, HID, false><<<(N + 15) / 16, 256, 0, stream>>>(bufB, W2, nullptr, bufA, N);          // t2 -> bufA
    gather_kernel<HID, true><<<(N + 3) / 4, 256, 0, stream>>>(bufA, dinv, row_ptr, ep, b2, bufB, N);      // h2 -> bufB

    // ---- layer 3: t3 = h2 @ W3 ; h3 = relu(A_hat t3 + b3) ----
    gemm_kernel<HID, OUT3, false><<<(N + 31) / 32, 256, 0, stream>>>(bufB, W3, nullptr, bufA, N);         // t3 -> bufA
    gather_kernel<OUT3, true><<<(N + 7) / 8, 256, 0, stream>>>(bufA, dinv, row_ptr, ep, b3, bufB, N);     // h3 -> bufB

    // ---- pool + head ----
    pool_kernel<<<256, 256, 0, stream>>>(bufB, batch, N, pool);
    head_kernel<<<1, 256, 0, stream>>>(pool, Wh1, bh1, Wh2, bh2, out);
}